// Round 10
// baseline (397.922 us; speedup 1.0000x reference)
//
#include <hip/hip_runtime.h>

#define NB 4
#define NS 1024
#define NH 256
#define NR 65536
#define NF 768
#define NK 512

typedef __attribute__((ext_vector_type(8))) short bf16x8;
typedef __attribute__((ext_vector_type(4))) float f32x4;

static __device__ __forceinline__ unsigned short f2bf(float f) {
  unsigned int u = __builtin_bit_cast(unsigned int, f);
  u += 0x7FFFu + ((u >> 16) & 1u);   // RTNE
  return (unsigned short)(u >> 16);
}

// HW packed convert: lo = bf16(a), hi = bf16(b), RTNE.
static __device__ __forceinline__ unsigned cvt_pk(float a, float b) {
  unsigned r;
  asm("v_cvt_pk_bf16_f32 %0, %1, %2" : "=v"(r) : "v"(a), "v"(b));
  return r;
}

// Raw barrier: lgkmcnt(0) only -- in-flight global loads survive it.
#define BARRIER()                                            \
  do {                                                       \
    asm volatile("s_waitcnt lgkmcnt(0)" ::: "memory");       \
    __builtin_amdgcn_s_barrier();                            \
    asm volatile("" ::: "memory");                           \
  } while (0)

// Combined prep (R5 16x16 fragment layouts): blocks [0,192) pack W1,
// [192,288) pack W2, block 288 detects rel_ids element width.
__global__ void prep_all(const float* __restrict__ w1, const float* __restrict__ w2,
                         const int* __restrict__ ids,
                         unsigned short* __restrict__ w1f,
                         unsigned short* __restrict__ w2f,
                         int* __restrict__ flag) {
  int bid = blockIdx.x;
  if (bid < 192) {
    // W1F unit u = (((c*4 + w)*2 + half)*16 + kk)*64 + lane holds
    // W1col[row = c*128+w*32+half*16+(lane&15)][k = kk*32+(lane>>4)*8 +0..7]
    int t = bid * 256 + threadIdx.x;
    int l = t & 63;
    int kk = (t >> 6) & 15;
    int half = (t >> 10) & 1;
    int w = (t >> 11) & 3;
    int c = t >> 13;
    int row = c * 128 + w * 32 + half * 16 + (l & 15);
    int k0 = kk * 32 + (l >> 4) * 8;
    uint4 pk;
    unsigned short v[8];
#pragma unroll
    for (int j = 0; j < 8; ++j) v[j] = f2bf(w1[(size_t)(k0 + j) * NF + row]);
    pk.x = v[0] | ((unsigned)v[1] << 16);
    pk.y = v[2] | ((unsigned)v[3] << 16);
    pk.z = v[4] | ((unsigned)v[5] << 16);
    pk.w = v[6] | ((unsigned)v[7] << 16);
    *(uint4*)(w1f + (size_t)t * 8) = pk;
  } else if (bid < 288) {
    // W2F unit u = (((w*4 + nj)*6 + c)*4 + kq)*64 + lane holds
    // W2col[row = w*64+nj*16+(lane&15)][k = c*128+kq*32+(lane>>4)*8 +0..7]
    int t = (bid - 192) * 256 + threadIdx.x;
    int l = t & 63;
    int kq = (t >> 6) & 3;
    int rest = t >> 8;
    int c = rest % 6;
    int wn = rest / 6;
    int nj = wn & 3;
    int w = wn >> 2;
    int row = w * 64 + nj * 16 + (l & 15);
    int k = c * 128 + kq * 32 + (l >> 4) * 8;
    uint4 pk;
    unsigned short v[8];
#pragma unroll
    for (int j = 0; j < 8; ++j) v[j] = f2bf(w2[(size_t)(k + j) * NH + row]);
    pk.x = v[0] | ((unsigned)v[1] << 16);
    pk.y = v[2] | ((unsigned)v[3] << 16);
    pk.z = v[4] | ((unsigned)v[5] << 16);
    pk.w = v[6] | ((unsigned)v[7] << 16);
    *(uint4*)(w2f + (size_t)t * 8) = pk;
  } else {
    __shared__ int anynz;
    if (threadIdx.x == 0) anynz = 0;
    __syncthreads();
    int acc = 0;
    for (int i = threadIdx.x; i < 8192; i += 256) acc |= ids[2 * i + 1];
    if (acc != 0) atomicOr(&anynz, 1);
    __syncthreads();
    if (threadIdx.x == 0) flag[0] = (anynz == 0) ? 1 : 0;  // 1 => int64
  }
}

// Fused: gather -> 3x pair{ G1(ca,cb) ; 4 phases of [G2 sub-pass || pack-half] }
// -> final G2 sub-pass -> epilogue. 64 rows/block, 4 waves, N-split.
// Hs ping-pong (2 x 8KB half-chunk buffers) fills every barrier-to-barrier
// phase with 32 MFMAs: the MFMA-free pack bubbles of R5 are eliminated.
__global__ __launch_bounds__(256, 2)
void fused_relffn(const float* __restrict__ span, const int* __restrict__ ids,
                  const float* __restrict__ b1, const float* __restrict__ b2,
                  const unsigned short* __restrict__ w1f,
                  const unsigned short* __restrict__ w2f,
                  const int* __restrict__ flagp, float* __restrict__ out) {
  __shared__ __align__(16) unsigned short As[64 * 512];    // 64 KB, swizzled
  __shared__ __align__(16) unsigned short Hb[2][64 * 64];  // 2 x 8 KB ping-pong

  const int tid = threadIdx.x;
  const int blk = blockIdx.x;
  const int bb = blk >> 10;              // batch
  const int r0 = (blk & 1023) << 6;      // first relation row
  const int lane = tid & 63;
  const int w = tid >> 6;                // wave 0..3
  const int l15 = lane & 15;
  const int lq = lane >> 4;              // 0..3
  const int half = w >> 1;               // pack half: 0 = cols 0..63, 1 = 64..127
  const int wl = w & 1;                  // col offset within half (0 or 32)
  const int is64 = flagp[0];

  // Packed W1 base: + c*65536 per chunk; half1 at +8192; + kk*512.
  const unsigned short* w1base = w1f + w * 16384 + lane * 8;
  // Packed W2 base: + nj*12288 + c*2048 + kq*512.
  const unsigned short* w2base = w2f + w * 49152 + lane * 8;

  // pair-0 wf prologue: in flight across gather + barrier.
  bf16x8 wfa[2][2], wfb[2][2];
#pragma unroll
  for (int d = 0; d < 2; ++d) {
    wfa[d][0] = *(const bf16x8*)(w1base + d * 512);
    wfa[d][1] = *(const bf16x8*)(w1base + 8192 + d * 512);
    wfb[d][0] = *(const bf16x8*)(w1base + 65536 + d * 512);
    wfb[d][1] = *(const bf16x8*)(w1base + 65536 + 8192 + d * 512);
  }

  // ---- gather A tile: ids preloaded, then unrolled load/convert ----
  {
    const long pair0 = ((long)bb * NR + r0) * 2;
    int idv[16];
#pragma unroll
    for (int j = 0; j < 16; ++j) {
      int g = tid + j * 256;
      int row = g >> 6;
      int kc = g & 63;
      long pidx = pair0 + row * 2 + (kc >> 5);
      idv[j] = is64 ? ids[pidx * 2] : ids[pidx];
    }
#pragma unroll
    for (int j = 0; j < 16; ++j) {
      int g = tid + j * 256;
      int row = g >> 6;
      int kc = g & 63;
      const float* src = span + ((size_t)bb * NS + idv[j]) * NH + (kc & 31) * 8;
      float4 v0 = *(const float4*)src;
      float4 v1 = *(const float4*)(src + 4);
      uint4 pk;
      pk.x = cvt_pk(v0.x, v0.y);
      pk.y = cvt_pk(v0.z, v0.w);
      pk.z = cvt_pk(v1.x, v1.y);
      pk.w = cvt_pk(v1.z, v1.w);
      int idx = row * 512 + ((kc * 8) ^ ((row & 7) << 3));  // XOR swizzle
      *(uint4*)&As[idx] = pk;
    }
  }
  BARRIER();

  f32x4 acc2[4][4];
#pragma unroll
  for (int mi = 0; mi < 4; ++mi)
#pragma unroll
    for (int nj = 0; nj < 4; ++nj) {
      f32x4 z = {0.f, 0.f, 0.f, 0.f};
      acc2[mi][nj] = z;
    }

  bf16x8 vf[2][4];   // current G2 sub-pass W2 fragments [kqL][nj]

  // load vf for sub-pass (c_, kq pair starting q0_)
  auto VFLOAD = [&](int c_, int q0_) {
    const unsigned short* p = w2base + c_ * 2048;
#pragma unroll
    for (int kqL = 0; kqL < 2; ++kqL)
#pragma unroll
      for (int nj = 0; nj < 4; ++nj)
        vf[kqL][nj] = *(const bf16x8*)(p + (q0_ + kqL) * 512 + nj * 12288);
  };

  // G2 sub-pass: read 8 hf frags from bufp, then (after optional pack) 32 MFMA.
  auto G2READ = [&](bf16x8 hf[2][4], const unsigned short* bufp) {
#pragma unroll
    for (int mi = 0; mi < 4; ++mi) {
      int row = mi * 16 + l15;
      int sz = (row & 7) << 3;
      hf[0][mi] = *(const bf16x8*)&bufp[row * 64 + ((lq * 8) ^ sz)];
      hf[1][mi] = *(const bf16x8*)&bufp[row * 64 + ((32 + lq * 8) ^ sz)];
    }
  };
  auto G2MFMA = [&](bf16x8 hf[2][4]) {
    __builtin_amdgcn_s_setprio(1);
#pragma unroll
    for (int kqL = 0; kqL < 2; ++kqL)
#pragma unroll
      for (int mi = 0; mi < 4; ++mi)
#pragma unroll
        for (int nj = 0; nj < 4; ++nj)
          acc2[mi][nj] = __builtin_amdgcn_mfma_f32_16x16x32_bf16(vf[kqL][nj], hf[kqL][mi], acc2[mi][nj], 0, 0, 0);
    __builtin_amdgcn_s_setprio(0);
  };

  // pack this wave's 32-col slice of chunk c_ into bufp (its half-buffer).
  auto PACK = [&](const f32x4 acc1[4][2], int c_, unsigned short* bufp) {
#pragma unroll
    for (int ni = 0; ni < 2; ++ni) {
      int n0 = c_ * 128 + w * 32 + ni * 16 + lq * 4;
      float4 bv = *(const float4*)(b1 + n0);
#pragma unroll
      for (int mi = 0; mi < 4; ++mi) {
        f32x4 a = acc1[mi][ni];
        float x0 = fmaxf(a[0] + bv.x, 0.0f);
        float x1 = fmaxf(a[1] + bv.y, 0.0f);
        float x2 = fmaxf(a[2] + bv.z, 0.0f);
        float x3 = fmaxf(a[3] + bv.w, 0.0f);
        int m = mi * 16 + l15;
        int nl = wl * 32 + ni * 16 + lq * 4;   // local col within half-buffer
        uint2 pk;
        pk.x = cvt_pk(x0, x1);
        pk.y = cvt_pk(x2, x3);
        *(uint2*)&bufp[m * 64 + (nl ^ ((m & 7) << 3))] = pk;
      }
    }
  };

  for (int cp = 0; cp < 3; ++cp) {
    const int ca = cp * 2, cb = ca + 1;
    const unsigned short* wpa = w1base + ca * 65536;
    const unsigned short* wpb = w1base + cb * 65536;

    // ---- G1 pair sweep (identical to R5): one af sweep feeds ca and cb ----
    f32x4 acc1a[4][2], acc1b[4][2];
#pragma unroll
    for (int mi = 0; mi < 4; ++mi)
#pragma unroll
      for (int ni = 0; ni < 2; ++ni) {
        f32x4 z = {0.f, 0.f, 0.f, 0.f};
        acc1a[mi][ni] = z;
        acc1b[mi][ni] = z;
      }
    bf16x8 afp[2][4];
#pragma unroll
    for (int mi = 0; mi < 4; ++mi) {
      int row = mi * 16 + l15;
      afp[0][mi] = *(const bf16x8*)&As[row * 512 + ((lq * 8) ^ ((row & 7) << 3))];
    }
#pragma unroll
    for (int kk = 0; kk < 16; ++kk) {
      const int cur = kk & 1;
      if (kk < 15) {
#pragma unroll
        for (int mi = 0; mi < 4; ++mi) {
          int row = mi * 16 + l15;
          int kidx = (kk + 1) * 32 + lq * 8;
          afp[cur ^ 1][mi] = *(const bf16x8*)&As[row * 512 + (kidx ^ ((row & 7) << 3))];
        }
      }
      bf16x8 ca0 = wfa[cur][0], ca1 = wfa[cur][1];
      bf16x8 cb0 = wfb[cur][0], cb1 = wfb[cur][1];
      if (kk < 14) {
        wfa[cur][0] = *(const bf16x8*)(wpa + (kk + 2) * 512);
        wfa[cur][1] = *(const bf16x8*)(wpa + 8192 + (kk + 2) * 512);
        wfb[cur][0] = *(const bf16x8*)(wpb + (kk + 2) * 512);
        wfb[cur][1] = *(const bf16x8*)(wpb + 8192 + (kk + 2) * 512);
      }
      __builtin_amdgcn_s_setprio(1);
#pragma unroll
      for (int mi = 0; mi < 4; ++mi) {
        bf16x8 a = afp[cur][mi];
        acc1a[mi][0] = __builtin_amdgcn_mfma_f32_16x16x32_bf16(ca0, a, acc1a[mi][0], 0, 0, 0);
        acc1a[mi][1] = __builtin_amdgcn_mfma_f32_16x16x32_bf16(ca1, a, acc1a[mi][1], 0, 0, 0);
        acc1b[mi][0] = __builtin_amdgcn_mfma_f32_16x16x32_bf16(cb0, a, acc1b[mi][0], 0, 0, 0);
        acc1b[mi][1] = __builtin_amdgcn_mfma_f32_16x16x32_bf16(cb1, a, acc1b[mi][1], 0, 0, 0);
      }
      __builtin_amdgcn_s_setprio(0);
    }

    // post-sweep: next pair's wf prologue (flies across all phases below)
    if (cp < 2) {
      const unsigned short* npa = w1base + (ca + 2) * 65536;
      const unsigned short* npb = w1base + (cb + 2) * 65536;
#pragma unroll
      for (int d = 0; d < 2; ++d) {
        wfa[d][0] = *(const bf16x8*)(npa + d * 512);
        wfa[d][1] = *(const bf16x8*)(npa + 8192 + d * 512);
        wfb[d][0] = *(const bf16x8*)(npb + d * 512);
        wfb[d][1] = *(const bf16x8*)(npb + 8192 + d * 512);
      }
    }

    // ---- PHASE 1: [deferred G2(cb_prev, kq23, buf1)] || pack-lo(ca)->buf0 ----
    if (cp > 0) {
      VFLOAD(ca - 1, 2);
      bf16x8 hf[2][4];
      G2READ(hf, &Hb[1][0]);
      if (half == 0) PACK(acc1a, ca, &Hb[0][0]);
      G2MFMA(hf);
    } else {
      if (half == 0) PACK(acc1a, ca, &Hb[0][0]);
    }
    VFLOAD(ca, 0);
    BARRIER();

    // ---- PHASE 2: G2(ca, kq01, buf0) || pack-hi(ca)->buf1 ----
    {
      bf16x8 hf[2][4];
      G2READ(hf, &Hb[0][0]);
      if (half == 1) PACK(acc1a, ca, &Hb[1][0]);
      G2MFMA(hf);
    }
    VFLOAD(ca, 2);
    BARRIER();

    // ---- PHASE 3: G2(ca, kq23, buf1) || pack-lo(cb)->buf0 ----
    {
      bf16x8 hf[2][4];
      G2READ(hf, &Hb[1][0]);
      if (half == 0) PACK(acc1b, cb, &Hb[0][0]);
      G2MFMA(hf);
    }
    VFLOAD(cb, 0);
    BARRIER();

    // ---- PHASE 4: G2(cb, kq01, buf0) || pack-hi(cb)->buf1 ----
    {
      bf16x8 hf[2][4];
      G2READ(hf, &Hb[0][0]);
      if (half == 1) PACK(acc1b, cb, &Hb[1][0]);
      G2MFMA(hf);
    }
    if (cp == 2) VFLOAD(5, 2);
    BARRIER();
    // G2(cb, kq23, buf1) deferred into next pair's phase 1 (or final below)
  }

  // ---- final deferred sub-pass: G2(5, kq23, buf1) ----
  {
    bf16x8 hf[2][4];
    G2READ(hf, &Hb[1][0]);
    G2MFMA(hf);
  }

  // ---- epilogue: +b2, float4 stores (lane owns 4 consecutive nout) ----
#pragma unroll
  for (int nj = 0; nj < 4; ++nj) {
    int n0 = w * 64 + nj * 16 + lq * 4;
    float4 bv = *(const float4*)(b2 + n0);
#pragma unroll
    for (int mi = 0; mi < 4; ++mi) {
      int m = mi * 16 + l15;
      f32x4 a = acc2[mi][nj];
      float4 o;
      o.x = a[0] + bv.x; o.y = a[1] + bv.y; o.z = a[2] + bv.z; o.w = a[3] + bv.w;
      *(float4*)(out + ((size_t)bb * NR + r0 + m) * NH + n0) = o;
    }
  }
}

extern "C" void kernel_launch(void* const* d_in, const int* in_sizes, int n_in,
                              void* d_out, int out_size, void* d_ws, size_t ws_size,
                              hipStream_t stream) {
  const float* span = (const float*)d_in[0];
  const int* ids = (const int*)d_in[1];
  const float* W1 = (const float*)d_in[2];
  const float* b1 = (const float*)d_in[3];
  const float* W2 = (const float*)d_in[4];
  const float* b2 = (const float*)d_in[5];
  float* out = (float*)d_out;

  char* ws = (char*)d_ws;
  int* flag = (int*)ws;
  unsigned short* w1f = (unsigned short*)(ws + 64);                    // 49152*16B
  unsigned short* w2f = (unsigned short*)(ws + 64 + NF * NK * 2);      // 24576*16B

  prep_all<<<289, 256, 0, stream>>>(W1, W2, ids, w1f, w2f, flag);
  fused_relffn<<<4096, 256, 0, stream>>>(span, ids, b1, b2, w1f, w2f, flag, out);
}

// Round 11
// 305.543 us; speedup vs baseline: 1.3023x; 1.3023x over previous
//
#include <hip/hip_runtime.h>

#define NB 4
#define NS 1024
#define NH 256
#define NR 65536
#define NF 768
#define NK 512

typedef __attribute__((ext_vector_type(8))) short bf16x8;
typedef __attribute__((ext_vector_type(4))) float f32x4;

static __device__ __forceinline__ unsigned short f2bf(float f) {
  unsigned int u = __builtin_bit_cast(unsigned int, f);
  u += 0x7FFFu + ((u >> 16) & 1u);   // RTNE
  return (unsigned short)(u >> 16);
}

// HW packed convert: lo = bf16(a), hi = bf16(b), RTNE.
static __device__ __forceinline__ unsigned cvt_pk(float a, float b) {
  unsigned r;
  asm("v_cvt_pk_bf16_f32 %0, %1, %2" : "=v"(r) : "v"(a), "v"(b));
  return r;
}

// Raw barrier: lgkmcnt(0) only -- in-flight global loads survive it.
#define BARRIER()                                            \
  do {                                                       \
    asm volatile("s_waitcnt lgkmcnt(0)" ::: "memory");       \
    __builtin_amdgcn_s_barrier();                            \
    asm volatile("" ::: "memory");                           \
  } while (0)

// Combined prep: blocks [0,192) pack W1, [192,288) pack W2, block 288 detects
// the rel_ids element width (int64 => odd int32 words all zero; ids < 1024).
__global__ void prep_all(const float* __restrict__ w1, const float* __restrict__ w2,
                         const int* __restrict__ ids,
                         unsigned short* __restrict__ w1f,
                         unsigned short* __restrict__ w2f,
                         int* __restrict__ flag) {
  int bid = blockIdx.x;
  if (bid < 192) {
    // W1F unit u = (((c*4 + w)*2 + half)*16 + kk)*64 + lane holds
    // W1col[row = c*128+w*32+half*16+(lane&15)][k = kk*32+(lane>>4)*8 +0..7]
    int t = bid * 256 + threadIdx.x;
    int l = t & 63;
    int kk = (t >> 6) & 15;
    int half = (t >> 10) & 1;
    int w = (t >> 11) & 3;
    int c = t >> 13;
    int row = c * 128 + w * 32 + half * 16 + (l & 15);
    int k0 = kk * 32 + (l >> 4) * 8;
    uint4 pk;
    unsigned short v[8];
#pragma unroll
    for (int j = 0; j < 8; ++j) v[j] = f2bf(w1[(size_t)(k0 + j) * NF + row]);
    pk.x = v[0] | ((unsigned)v[1] << 16);
    pk.y = v[2] | ((unsigned)v[3] << 16);
    pk.z = v[4] | ((unsigned)v[5] << 16);
    pk.w = v[6] | ((unsigned)v[7] << 16);
    *(uint4*)(w1f + (size_t)t * 8) = pk;
  } else if (bid < 288) {
    // W2F unit u = (((w*4 + nj)*6 + c)*4 + kq)*64 + lane holds
    // W2col[row = w*64+nj*16+(lane&15)][k = c*128+kq*32+(lane>>4)*8 +0..7]
    int t = (bid - 192) * 256 + threadIdx.x;
    int l = t & 63;
    int kq = (t >> 6) & 3;
    int rest = t >> 8;
    int c = rest % 6;
    int wn = rest / 6;
    int nj = wn & 3;
    int w = wn >> 2;
    int row = w * 64 + nj * 16 + (l & 15);
    int k = c * 128 + kq * 32 + (l >> 4) * 8;
    uint4 pk;
    unsigned short v[8];
#pragma unroll
    for (int j = 0; j < 8; ++j) v[j] = f2bf(w2[(size_t)(k + j) * NH + row]);
    pk.x = v[0] | ((unsigned)v[1] << 16);
    pk.y = v[2] | ((unsigned)v[3] << 16);
    pk.z = v[4] | ((unsigned)v[5] << 16);
    pk.w = v[6] | ((unsigned)v[7] << 16);
    *(uint4*)(w2f + (size_t)t * 8) = pk;
  } else {
    __shared__ int anynz;
    if (threadIdx.x == 0) anynz = 0;
    __syncthreads();
    int acc = 0;
    for (int i = threadIdx.x; i < 8192; i += 256) acc |= ids[2 * i + 1];
    if (acc != 0) atomicOr(&anynz, 1);
    __syncthreads();
    if (threadIdx.x == 0) flag[0] = (anynz == 0) ? 1 : 0;  // 1 => int64
  }
}

// Fused: gather -> GEMM1(relu,+b1) -> GEMM2(+b2), 64 rows per block, 4 waves.
// R5 structure (chunk-pair GEMM1, af/wf/hf rolling prefetch) + per-block
// chunk-pair ROTATION (rot = blk%3): co-resident blocks on a CU process the
// pairs in different order, anti-phasing their pack windows so one block's
// G1 MFMAs fill the other's MFMA-free phases (m114 co-scheduling).
// acc2 is a sum over chunks -> order is free.
__global__ __launch_bounds__(256, 2)
void fused_relffn(const float* __restrict__ span, const int* __restrict__ ids,
                  const float* __restrict__ b1, const float* __restrict__ b2,
                  const unsigned short* __restrict__ w1f,
                  const unsigned short* __restrict__ w2f,
                  const int* __restrict__ flagp, float* __restrict__ out) {
  __shared__ __align__(16) unsigned short As[64 * 512];  // 64 KB, swizzled
  __shared__ __align__(16) unsigned short Hs[64 * 128];  // 16 KB, swizzled

  const int tid = threadIdx.x;
  const int blk = blockIdx.x;
  const int bb = blk >> 10;              // batch
  const int r0 = (blk & 1023) << 6;      // first relation row
  const int lane = tid & 63;
  const int w = tid >> 6;                // wave 0..3
  const int l15 = lane & 15;
  const int lq = lane >> 4;              // 0..3
  const int is64 = flagp[0];
  const int rot = blk % 3;               // pair-order rotation (phase decorrelation)

  // Packed W1 base: + c*65536 per chunk; half1 at +8192; + kk*512.
  const unsigned short* w1base = w1f + w * 16384 + lane * 8;
  // Packed W2 base: + nj*12288 + c*2048 + kq*512.
  const unsigned short* w2base = w2f + w * 49152 + lane * 8;

  // ---- prefetch FIRST (rotated) pair's wf prologue BEFORE the gather ----
  bf16x8 wfa[2][2], wfb[2][2];   // [depth][half]
  {
    const unsigned short* wpa0 = w1base + (rot * 2) * 65536;
    const unsigned short* wpb0 = w1base + (rot * 2 + 1) * 65536;
#pragma unroll
    for (int d = 0; d < 2; ++d) {
      wfa[d][0] = *(const bf16x8*)(wpa0 + d * 512);
      wfa[d][1] = *(const bf16x8*)(wpa0 + 8192 + d * 512);
      wfb[d][0] = *(const bf16x8*)(wpb0 + d * 512);
      wfb[d][1] = *(const bf16x8*)(wpb0 + 8192 + d * 512);
    }
  }

  // ---- gather A tile: ids preloaded, then unrolled load/convert ----
  {
    const long pair0 = ((long)bb * NR + r0) * 2;
    int idv[16];
#pragma unroll
    for (int j = 0; j < 16; ++j) {
      int g = tid + j * 256;
      int row = g >> 6;
      int kc = g & 63;
      long pidx = pair0 + row * 2 + (kc >> 5);
      idv[j] = is64 ? ids[pidx * 2] : ids[pidx];
    }
#pragma unroll
    for (int j = 0; j < 16; ++j) {
      int g = tid + j * 256;
      int row = g >> 6;
      int kc = g & 63;
      const float* src = span + ((size_t)bb * NS + idv[j]) * NH + (kc & 31) * 8;
      float4 v0 = *(const float4*)src;
      float4 v1 = *(const float4*)(src + 4);
      uint4 pk;
      pk.x = cvt_pk(v0.x, v0.y);
      pk.y = cvt_pk(v0.z, v0.w);
      pk.z = cvt_pk(v1.x, v1.y);
      pk.w = cvt_pk(v1.z, v1.w);
      int idx = row * 512 + ((kc * 8) ^ ((row & 7) << 3));  // XOR swizzle
      *(uint4*)&As[idx] = pk;
    }
  }
  BARRIER();

  f32x4 acc2[4][4];
#pragma unroll
  for (int mi = 0; mi < 4; ++mi)
#pragma unroll
    for (int nj = 0; nj < 4; ++nj) {
      f32x4 z = {0.f, 0.f, 0.f, 0.f};
      acc2[mi][nj] = z;
    }

  for (int cpi = 0; cpi < 3; ++cpi) {
    const int cp = (cpi + rot) % 3;       // rotated pair index
    const int ca = cp * 2, cb = ca + 1;
    const unsigned short* wpa = w1base + ca * 65536;
    const unsigned short* wpb = w1base + cb * 65536;

    // ---- GEMM1 pair: one af sweep feeds chunks ca and cb ----
    f32x4 acc1a[4][2], acc1b[4][2];
#pragma unroll
    for (int mi = 0; mi < 4; ++mi)
#pragma unroll
      for (int ni = 0; ni < 2; ++ni) {
        f32x4 z = {0.f, 0.f, 0.f, 0.f};
        acc1a[mi][ni] = z;
        acc1b[mi][ni] = z;
      }

    bf16x8 afp[2][4];              // af double buffer
#pragma unroll
    for (int mi = 0; mi < 4; ++mi) {
      int row = mi * 16 + l15;
      afp[0][mi] = *(const bf16x8*)&As[row * 512 + ((lq * 8) ^ ((row & 7) << 3))];
    }

#pragma unroll
    for (int kk = 0; kk < 16; ++kk) {
      const int cur = kk & 1;
      if (kk < 15) {   // prefetch next kk's af
#pragma unroll
        for (int mi = 0; mi < 4; ++mi) {
          int row = mi * 16 + l15;
          int kidx = (kk + 1) * 32 + lq * 8;
          afp[cur ^ 1][mi] = *(const bf16x8*)&As[row * 512 + (kidx ^ ((row & 7) << 3))];
        }
      }
      bf16x8 ca0 = wfa[cur][0], ca1 = wfa[cur][1];
      bf16x8 cb0 = wfb[cur][0], cb1 = wfb[cur][1];
      if (kk < 14) {   // refill wf slot with kk+2
        wfa[cur][0] = *(const bf16x8*)(wpa + (kk + 2) * 512);
        wfa[cur][1] = *(const bf16x8*)(wpa + 8192 + (kk + 2) * 512);
        wfb[cur][0] = *(const bf16x8*)(wpb + (kk + 2) * 512);
        wfb[cur][1] = *(const bf16x8*)(wpb + 8192 + (kk + 2) * 512);
      }
      __builtin_amdgcn_s_setprio(1);
#pragma unroll
      for (int mi = 0; mi < 4; ++mi) {
        bf16x8 a = afp[cur][mi];
        acc1a[mi][0] = __builtin_amdgcn_mfma_f32_16x16x32_bf16(ca0, a, acc1a[mi][0], 0, 0, 0);
        acc1a[mi][1] = __builtin_amdgcn_mfma_f32_16x16x32_bf16(ca1, a, acc1a[mi][1], 0, 0, 0);
        acc1b[mi][0] = __builtin_amdgcn_mfma_f32_16x16x32_bf16(cb0, a, acc1b[mi][0], 0, 0, 0);
        acc1b[mi][1] = __builtin_amdgcn_mfma_f32_16x16x32_bf16(cb1, a, acc1b[mi][1], 0, 0, 0);
      }
      __builtin_amdgcn_s_setprio(0);
    }

    // next (rotated) pair's wf prologue; survives the barriers below
    if (cpi < 2) {
      const int cpn = (cpi + 1 + rot) % 3;
      const unsigned short* npa = w1base + (cpn * 2) * 65536;
      const unsigned short* npb = w1base + (cpn * 2 + 1) * 65536;
#pragma unroll
      for (int d = 0; d < 2; ++d) {
        wfa[d][0] = *(const bf16x8*)(npa + d * 512);
        wfa[d][1] = *(const bf16x8*)(npa + 8192 + d * 512);
        wfb[d][0] = *(const bf16x8*)(npb + d * 512);
        wfb[d][1] = *(const bf16x8*)(npb + 8192 + d * 512);
      }
    }

    // ---- chunk ca: pack -> GEMM2; then chunk cb ----
#pragma unroll
    for (int half = 0; half < 2; ++half) {
      const int c = half ? cb : ca;
      BARRIER();   // prior chunk's Hs reads done before overwrite
#pragma unroll
      for (int ni = 0; ni < 2; ++ni) {
        int n0 = c * 128 + w * 32 + ni * 16 + lq * 4;
        float4 bv = *(const float4*)(b1 + n0);
#pragma unroll
        for (int mi = 0; mi < 4; ++mi) {
          f32x4 a = half ? acc1b[mi][ni] : acc1a[mi][ni];
          float x0 = fmaxf(a[0] + bv.x, 0.0f);
          float x1 = fmaxf(a[1] + bv.y, 0.0f);
          float x2 = fmaxf(a[2] + bv.z, 0.0f);
          float x3 = fmaxf(a[3] + bv.w, 0.0f);
          int m = mi * 16 + l15;
          int nl0 = w * 32 + ni * 16 + lq * 4;
          uint2 pk;
          pk.x = cvt_pk(x0, x1);
          pk.y = cvt_pk(x2, x3);
          *(uint2*)&Hs[m * 128 + (nl0 ^ ((m & 7) << 3))] = pk;
        }
      }
      BARRIER();
      const unsigned short* w2p = w2base + c * 2048;
#pragma unroll
      for (int kq = 0; kq < 4; ++kq) {
        bf16x8 vf[4];
#pragma unroll
        for (int nj = 0; nj < 4; ++nj)
          vf[nj] = *(const bf16x8*)(w2p + nj * 12288 + kq * 512);
        bf16x8 hf[4];
#pragma unroll
        for (int mi = 0; mi < 4; ++mi) {
          int row = mi * 16 + l15;
          int kidx = kq * 32 + lq * 8;
          hf[mi] = *(const bf16x8*)&Hs[row * 128 + (kidx ^ ((row & 7) << 3))];
        }
        __builtin_amdgcn_s_setprio(1);
#pragma unroll
        for (int mi = 0; mi < 4; ++mi)
#pragma unroll
          for (int nj = 0; nj < 4; ++nj)
            acc2[mi][nj] = __builtin_amdgcn_mfma_f32_16x16x32_bf16(vf[nj], hf[mi], acc2[mi][nj], 0, 0, 0);
        __builtin_amdgcn_s_setprio(0);
      }
    }
  }

  // ---- epilogue: +b2, float4 stores (lane owns 4 consecutive nout) ----
#pragma unroll
  for (int nj = 0; nj < 4; ++nj) {
    int n0 = w * 64 + nj * 16 + lq * 4;
    float4 bv = *(const float4*)(b2 + n0);
#pragma unroll
    for (int mi = 0; mi < 4; ++mi) {
      int m = mi * 16 + l15;
      f32x4 a = acc2[mi][nj];
      float4 o;
      o.x = a[0] + bv.x; o.y = a[1] + bv.y; o.z = a[2] + bv.z; o.w = a[3] + bv.w;
      *(float4*)(out + ((size_t)bb * NR + r0 + m) * NH + n0) = o;
    }
  }
}

extern "C" void kernel_launch(void* const* d_in, const int* in_sizes, int n_in,
                              void* d_out, int out_size, void* d_ws, size_t ws_size,
                              hipStream_t stream) {
  const float* span = (const float*)d_in[0];
  const int* ids = (const int*)d_in[1];
  const float* W1 = (const float*)d_in[2];
  const float* b1 = (const float*)d_in[3];
  const float* W2 = (const float*)d_in[4];
  const float* b2 = (const float*)d_in[5];
  float* out = (float*)d_out;

  char* ws = (char*)d_ws;
  int* flag = (int*)ws;
  unsigned short* w1f = (unsigned short*)(ws + 64);                    // 49152*16B
  unsigned short* w2f = (unsigned short*)(ws + 64 + NF * NK * 2);      // 24576*16B

  prep_all<<<289, 256, 0, stream>>>(W1, W2, ids, w1f, w2f, flag);
  fused_relffn<<<4096, 256, 0, stream>>>(span, ids, b1, b2, w1f, w2f, flag, out);
}